// Round 4
// baseline (213.274 us; speedup 1.0000x reference)
//
#include <hip/hip_runtime.h>
#include <hip/hip_bf16.h>

typedef __attribute__((ext_vector_type(8))) short short8;
typedef __attribute__((ext_vector_type(4))) float floatx4;
typedef unsigned short ushort_t;
typedef unsigned int uint_t;

#define DOUT   256
#define KPAD   864          // 320 + 320 + 224 (segments padded to x32)
#define XPITCH 904          // ushorts per LDS row (452 dwords; 452%32=4 -> bank-safe)
#define TB     16           // tokens per block
#define NTOK   16384        // 32*512
#define NPREP_T 27          // transpose blocks (864/32)
#define NPREP_U 225         // 225*4 = 900 >= 899 kp rows (u[0..896) + 3 biases)

static __device__ inline uint_t pack2bf(float x, float y) {
    __hip_bfloat162 h = __float22bfloat162_rn(make_float2(x, y));
    return *(uint_t*)&h;
}

// ---------------------------------------------------------------------------
// Merged prep:
//  blocks [0, 27):      Wt[n][k] = bf16(W_cat[k][n])  (padded K, zeros in pads)
//  blocks [27, 27+225): u[k] = W_cat[k,:] . Wa  (u zero-padded to 896);
//                       lb[n] = b_n . Wa + ba
// ---------------------------------------------------------------------------
__global__ __launch_bounds__(256) void k_prep(
    const float* __restrict__ W0, const float* __restrict__ W1,
    const float* __restrict__ W2,
    const float* __restrict__ b0, const float* __restrict__ b1,
    const float* __restrict__ b2,
    const float* __restrict__ Wa, const float* __restrict__ ba,
    float* __restrict__ u, float* __restrict__ lb, ushort_t* __restrict__ Wt)
{
    __shared__ ushort_t tile[32][256];
    int tid = threadIdx.x;
    if (blockIdx.x < NPREP_T) {
        int k0 = blockIdx.x * 32;
        for (int idx = tid; idx < 32 * 256; idx += 256) {
            int kk = idx >> 8, d = idx & 255;
            int kp = k0 + kk;
            float v = 0.f;
            const float* src = nullptr;
            if (kp < 320)      { if (kp < 300) src = W0 + kp * DOUT; }
            else if (kp < 640) { int o = kp - 320; if (o < 300) src = W1 + o * DOUT; }
            else               { int o = kp - 640; if (o < 200) src = W2 + o * DOUT; }
            if (src) v = src[d];
            tile[kk][d] = (ushort_t)(pack2bf(v, 0.f) & 0xFFFFu);
        }
        __syncthreads();
        int d = tid;
        #pragma unroll
        for (int g = 0; g < 4; ++g) {
            union { uint4 v; ushort_t s[8]; } p;
            #pragma unroll
            for (int j = 0; j < 8; ++j) p.s[j] = tile[g * 8 + j][d];
            *(uint4*)(Wt + (size_t)d * KPAD + k0 + g * 8) = p.v;
        }
    } else {
        int lane = tid & 63;
        int w = tid >> 6;
        int kp = (blockIdx.x - NPREP_T) * 4 + w;   // 0..899
        if (kp > 898) return;
        const float* row = nullptr;
        if (kp < 320)       { if (kp < 300) row = W0 + kp * DOUT; }
        else if (kp < 640)  { int o = kp - 320; if (o < 300) row = W1 + o * DOUT; }
        else if (kp < 864)  { int o = kp - 640; if (o < 200) row = W2 + o * DOUT; }
        else if (kp >= 896) { int n = kp - 896; row = (n == 0) ? b0 : ((n == 1) ? b1 : b2); }
        // kp in [864,896): row stays null -> u[kp] = 0 (pad region)
        float acc = 0.f;
        if (row) {
            #pragma unroll
            for (int j = lane; j < DOUT; j += 64)
                acc += row[j] * Wa[j];
        }
        for (int off = 32; off > 0; off >>= 1) acc += __shfl_down(acc, off);
        if (lane == 0) {
            if (kp < 896) u[kp] = acc;
            else          lb[kp - 896] = acc + ba[0];
        }
    }
}

// ---------------------------------------------------------------------------
// Main: batched gather(float4, fp32->bf16) + fused fp32 logits -> softmax ->
//       MFMA GEMM (3 segment accumulator sets) -> weighted epilogue.
// Block: 256 threads (4 waves), 16 tokens; grid 1024; ~5 blocks/CU.
// ---------------------------------------------------------------------------
#define MFMA_STEP(ACC, KC) {                                                   \
    short8 a0 = *(const short8*)&Xs[mrow][(KC) + kg8];                         \
    _Pragma("unroll")                                                          \
    for (int nt = 0; nt < 4; ++nt) {                                           \
        short8 bv = *(const short8*)(bp[nt] + (KC));                           \
        ACC[nt] = __builtin_amdgcn_mfma_f32_16x16x32_bf16(a0, bv, ACC[nt], 0, 0, 0); \
    }                                                                          \
}

__global__ __launch_bounds__(256, 5) void k_main(
    const int* __restrict__ ids,
    const float* __restrict__ E0, const float* __restrict__ E1,
    const float* __restrict__ E2,
    const float* __restrict__ b0, const float* __restrict__ b1,
    const float* __restrict__ b2,
    const float* __restrict__ u, const float* __restrict__ lb,
    const ushort_t* __restrict__ Wt,
    float* __restrict__ out)
{
    __shared__ __align__(16) ushort_t Xs[TB][XPITCH];   // 28928 B (bf16 tokens)
    __shared__ float alphaS[TB][4];                     // 256 B

    int tid = threadIdx.x;
    int tok0 = blockIdx.x * TB;

    // ---- batched gather: 16 threads per token; 14 float4 loads up front ----
    int trow = tid >> 4, sub = tid & 15;
    int id = ids[tok0 + trow];
    uint2* Xd2 = (uint2*)&Xs[trow][0];                  // 226 uint2 capacity
    const float4* E0v = (const float4*)E0;              // 75 per row
    const float4* E1v = (const float4*)E1;              // 75 per row
    const float4* E2v = (const float4*)E2;              // 50 per row
    float4 f4z = make_float4(0.f, 0.f, 0.f, 0.f);

    float4 g[14];
    {
        const float4* p0 = E0v + (size_t)id * 75;
        const float4* p1 = E1v + (size_t)id * 75;
        const float4* p2 = E2v + (size_t)id * 50;
        g[0] = p0[sub];      g[1] = p0[sub + 16];
        g[2] = p0[sub + 32]; g[3] = p0[sub + 48];
        g[4] = (sub < 11) ? p0[sub + 64] : f4z;
        g[5] = p1[sub];      g[6] = p1[sub + 16];
        g[7] = p1[sub + 32]; g[8] = p1[sub + 48];
        g[9] = (sub < 11) ? p1[sub + 64] : f4z;
        g[10] = p2[sub];      g[11] = p2[sub + 16];
        g[12] = p2[sub + 32];
        g[13] = (sub < 2) ? p2[sub + 48] : f4z;
    }

    // ---- consume: fused fp32 logit partials + bf16 pack into LDS ----
    float l0 = 0.f, l1 = 0.f, l2 = 0.f;
    #pragma unroll
    for (int j = 0; j < 5; ++j) {
        int i = sub + 16 * j;
        float4 t = g[j];
        float4 uu = *(const float4*)(u + 4 * i);
        l0 += t.x * uu.x + t.y * uu.y + t.z * uu.z + t.w * uu.w;
        Xd2[i] = make_uint2(pack2bf(t.x, t.y), pack2bf(t.z, t.w));
    }
    #pragma unroll
    for (int j = 0; j < 5; ++j) {
        int i = sub + 16 * j;
        float4 t = g[5 + j];
        float4 uu = *(const float4*)(u + 320 + 4 * i);
        l1 += t.x * uu.x + t.y * uu.y + t.z * uu.z + t.w * uu.w;
        Xd2[80 + i] = make_uint2(pack2bf(t.x, t.y), pack2bf(t.z, t.w));
    }
    #pragma unroll
    for (int j = 0; j < 4; ++j) {
        int i = sub + 16 * j;
        float4 t = g[10 + j];
        float4 uu = *(const float4*)(u + 640 + 4 * i);
        l2 += t.x * uu.x + t.y * uu.y + t.z * uu.z + t.w * uu.w;
        Xd2[160 + i] = make_uint2(pack2bf(t.x, t.y), pack2bf(t.z, t.w));
    }

    // 16-lane tree reduce (token's lanes contiguous within the wave)
    #pragma unroll
    for (int off = 8; off > 0; off >>= 1) {
        l0 += __shfl_down(l0, off);
        l1 += __shfl_down(l1, off);
        l2 += __shfl_down(l2, off);
    }
    if (sub == 0) {
        l0 += lb[0]; l1 += lb[1]; l2 += lb[2];
        float m = fmaxf(l0, fmaxf(l1, l2));
        float e0 = __expf(l0 - m), e1 = __expf(l1 - m), e2 = __expf(l2 - m);
        float inv = 1.f / (e0 + e1 + e2);
        alphaS[trow][0] = e0 * inv;
        alphaS[trow][1] = e1 * inv;
        alphaS[trow][2] = e2 * inv;
    }
    __syncthreads();

    // ---- MFMA GEMM: wave w owns n in [64w, 64w+64); one 16-row M-tile ----
    int lane = tid & 63;
    int w = tid >> 6;               // 0..3
    int mrow = lane & 15;
    int kg8 = (lane >> 4) * 8;

    const ushort_t* bp[4];
    #pragma unroll
    for (int nt = 0; nt < 4; ++nt)
        bp[nt] = Wt + (size_t)(w * 64 + nt * 16 + mrow) * KPAD + kg8;

    floatx4 acc0[4], acc1[4], acc2[4];
    #pragma unroll
    for (int nt = 0; nt < 4; ++nt) {
        floatx4 z = {0.f, 0.f, 0.f, 0.f};
        acc0[nt] = z; acc1[nt] = z; acc2[nt] = z;
    }

    #pragma unroll
    for (int kc = 0; kc < 320; kc += 32)   MFMA_STEP(acc0, kc);
    #pragma unroll
    for (int kc = 320; kc < 640; kc += 32) MFMA_STEP(acc1, kc);
    #pragma unroll
    for (int kc = 640; kc < 864; kc += 32) MFMA_STEP(acc2, kc);

    // ---- epilogue: out = a0*(p0+b0) + a1*(p1+b1) + a2*(p2+b2) (fp32) ----
    float bb0[4], bb1[4], bb2[4];
    #pragma unroll
    for (int nt = 0; nt < 4; ++nt) {
        int n = w * 64 + nt * 16 + mrow;
        bb0[nt] = b0[n];
        bb1[nt] = b1[n];
        bb2[nt] = b2[n];
    }
    #pragma unroll
    for (int r = 0; r < 4; ++r) {
        int tok = (lane >> 4) * 4 + r;
        float a0 = alphaS[tok][0], a1 = alphaS[tok][1], a2 = alphaS[tok][2];
        size_t rowoff = (size_t)(tok0 + tok) * DOUT;
        #pragma unroll
        for (int nt = 0; nt < 4; ++nt) {
            int n = w * 64 + nt * 16 + mrow;
            float v = a0 * (acc0[nt][r] + bb0[nt])
                    + a1 * (acc1[nt][r] + bb1[nt])
                    + a2 * (acc2[nt][r] + bb2[nt]);
            out[rowoff + n] = v;
        }
    }
}

extern "C" void kernel_launch(void* const* d_in, const int* in_sizes, int n_in,
                              void* d_out, int out_size, void* d_ws, size_t ws_size,
                              hipStream_t stream) {
    const int*   ids = (const int*)d_in[0];
    const float* E0  = (const float*)d_in[1];
    const float* E1  = (const float*)d_in[2];
    const float* E2  = (const float*)d_in[3];
    const float* W0  = (const float*)d_in[4];
    const float* b0  = (const float*)d_in[5];
    const float* W1  = (const float*)d_in[6];
    const float* b1  = (const float*)d_in[7];
    const float* W2  = (const float*)d_in[8];
    const float* b2  = (const float*)d_in[9];
    const float* Wa  = (const float*)d_in[10];
    const float* ba  = (const float*)d_in[11];

    float* u     = (float*)d_ws;                       // 896 floats (zero-padded)
    float* lb    = u + 896;                            // 3 floats
    ushort_t* Wt = (ushort_t*)((char*)d_ws + 4096);    // 256*864 bf16 = 432 KB

    k_prep<<<NPREP_T + NPREP_U, 256, 0, stream>>>(W0, W1, W2, b0, b1, b2, Wa, ba,
                                                  u, lb, Wt);
    k_main<<<NTOK / TB, 256, 0, stream>>>(ids, E0, E1, E2, b0, b1, b2, u, lb, Wt,
                                          (float*)d_out);
}

// Round 6
// 191.226 us; speedup vs baseline: 1.1153x; 1.1153x over previous
//
#include <hip/hip_runtime.h>
#include <hip/hip_bf16.h>

typedef __attribute__((ext_vector_type(8))) short short8;
typedef __attribute__((ext_vector_type(4))) float floatx4;
typedef unsigned short ushort_t;
typedef unsigned int uint_t;

#define DOUT   256
#define KPAD   864          // 320 + 320 + 224 (segments padded to x32)
#define XPITCH 872          // ushorts per LDS row (436 dwords; 218 uint2)
#define TB     32           // tokens per block
#define NTOK   16384        // 32*512
#define NPREP_T 27          // fragment-transpose blocks (864/32 k-slabs)
#define NPREP_U 225         // u/lb blocks

static __device__ inline uint_t pack2bf(float x, float y) {
    __hip_bfloat162 h = __float22bfloat162_rn(make_float2(x, y));
    return *(uint_t*)&h;
}
static __device__ inline ushort_t f2bf(float f) {
    union { float f; uint_t u; } a; a.f = f;
    uint_t u = a.u;
    return (ushort_t)((u + 0x7FFFu + ((u >> 16) & 1u)) >> 16);
}

// ---------------------------------------------------------------------------
// Merged prep.
//  blocks [0,27): Wtf fragment layout — for k-slab kc, element for (nt,lane,j):
//      Wtf[((nt*27 + kc)*64 + lane)*8 + j] = bf16(W_cat[kc*32 + (lane>>4)*8 + j]
//                                                      [nt*16 + (lane&15)])
//  blocks [27,27+225): u[k] = W_cat[k,:].Wa (zero-padded to 896); lb[n]=b_n.Wa+ba
// ---------------------------------------------------------------------------
__global__ __launch_bounds__(256) void k_prep(
    const float* __restrict__ W0, const float* __restrict__ W1,
    const float* __restrict__ W2,
    const float* __restrict__ b0, const float* __restrict__ b1,
    const float* __restrict__ b2,
    const float* __restrict__ Wa, const float* __restrict__ ba,
    float* __restrict__ u, float* __restrict__ lb, ushort_t* __restrict__ Wtf)
{
    __shared__ ushort_t tile[32][258];   // k-row x n-col, +2 pad
    int tid = threadIdx.x;
    if (blockIdx.x < NPREP_T) {
        int kc = blockIdx.x;
        for (int idx = tid; idx < 32 * 64; idx += 256) {   // float4 granules
            int kk = idx >> 6, c4 = idx & 63;
            int kp = kc * 32 + kk;
            float4 v = make_float4(0.f, 0.f, 0.f, 0.f);
            const float* src = nullptr;
            if (kp < 320)      { if (kp < 300) src = W0 + kp * DOUT; }
            else if (kp < 640) { int o = kp - 320; if (o < 300) src = W1 + o * DOUT; }
            else               { int o = kp - 640; if (o < 200) src = W2 + o * DOUT; }
            if (src) v = *(const float4*)(src + 4 * c4);
            tile[kk][4 * c4 + 0] = f2bf(v.x);
            tile[kk][4 * c4 + 1] = f2bf(v.y);
            tile[kk][4 * c4 + 2] = f2bf(v.z);
            tile[kk][4 * c4 + 3] = f2bf(v.w);
        }
        __syncthreads();
        int lane = tid & 63;
        int ntg = tid >> 6;                 // 0..3
        int kq = (lane >> 4) * 8;
        int nc = lane & 15;
        #pragma unroll
        for (int i = 0; i < 4; ++i) {
            int nt = ntg * 4 + i;
            union { uint4 v; ushort_t s[8]; } p;
            #pragma unroll
            for (int j = 0; j < 8; ++j) p.s[j] = tile[kq + j][nt * 16 + nc];
            *(uint4*)(Wtf + ((size_t)(nt * 27 + kc) * 64 + lane) * 8) = p.v;
        }
    } else {
        int lane = tid & 63;
        int w = tid >> 6;
        int kp = (blockIdx.x - NPREP_T) * 4 + w;   // 0..899
        if (kp > 898) return;
        const float* row = nullptr;
        if (kp < 320)       { if (kp < 300) row = W0 + kp * DOUT; }
        else if (kp < 640)  { int o = kp - 320; if (o < 300) row = W1 + o * DOUT; }
        else if (kp < 864)  { int o = kp - 640; if (o < 200) row = W2 + o * DOUT; }
        else if (kp >= 896) { int n = kp - 896; row = (n == 0) ? b0 : ((n == 1) ? b1 : b2); }
        float acc = 0.f;
        if (row) {
            #pragma unroll
            for (int j = lane; j < DOUT; j += 64)
                acc += row[j] * Wa[j];
        }
        for (int off = 32; off > 0; off >>= 1) acc += __shfl_down(acc, off);
        if (lane == 0) {
            if (kp < 896) u[kp] = acc;
            else          lb[kp - 896] = acc + ba[0];
        }
    }
}

// ---------------------------------------------------------------------------
// Main: batched gather -> logits/softmax -> alpha-scaled bf16 pack -> single-acc
//       MFMA GEMM with fragment-streamed B -> epilogue (+ alpha-weighted bias).
// Block: 512 threads (8 waves), 32 tokens; grid 512.
// ---------------------------------------------------------------------------
__global__ __launch_bounds__(512, 4) void k_main(
    const int* __restrict__ ids,
    const float* __restrict__ E0, const float* __restrict__ E1,
    const float* __restrict__ E2,
    const float* __restrict__ b0, const float* __restrict__ b1,
    const float* __restrict__ b2,
    const float* __restrict__ u, const float* __restrict__ lb,
    const ushort_t* __restrict__ Wtf,
    float* __restrict__ out)
{
    __shared__ __align__(16) ushort_t Xs[TB][XPITCH];   // 55808 B (alpha-scaled bf16)
    __shared__ float alphaS[TB][4];

    int tid = threadIdx.x;
    int tok0 = blockIdx.x * TB;

    // ---- batched gather: 16 threads/token; all 14 float4 loads pinned first ----
    int trow = tid >> 4, sub = tid & 15;
    int id = ids[tok0 + trow];
    uint2* Xd2 = (uint2*)&Xs[trow][0];
    const float4* p0 = (const float4*)E0 + (size_t)id * 75;
    const float4* p1 = (const float4*)E1 + (size_t)id * 75;
    const float4* p2 = (const float4*)E2 + (size_t)id * 50;
    float4 f4z = make_float4(0.f, 0.f, 0.f, 0.f);

    float4 g[14];
    g[0] = p0[sub];      g[1] = p0[sub + 16];
    g[2] = p0[sub + 32]; g[3] = p0[sub + 48];
    g[4] = (sub < 11) ? p0[sub + 64] : f4z;
    g[5] = p1[sub];      g[6] = p1[sub + 16];
    g[7] = p1[sub + 32]; g[8] = p1[sub + 48];
    g[9] = (sub < 11) ? p1[sub + 64] : f4z;
    g[10] = p2[sub];      g[11] = p2[sub + 16];
    g[12] = p2[sub + 32];
    g[13] = (sub < 2) ? p2[sub + 48] : f4z;
    __builtin_amdgcn_sched_barrier(0);   // keep all 14 loads issued before consume

    // ---- fp32 logit partials ----
    float l0 = 0.f, l1 = 0.f, l2 = 0.f;
    #pragma unroll
    for (int j = 0; j < 5; ++j) {
        float4 t = g[j], uu = *(const float4*)(u + 4 * (sub + 16 * j));
        l0 += t.x * uu.x + t.y * uu.y + t.z * uu.z + t.w * uu.w;
    }
    #pragma unroll
    for (int j = 0; j < 5; ++j) {
        float4 t = g[5 + j], uu = *(const float4*)(u + 320 + 4 * (sub + 16 * j));
        l1 += t.x * uu.x + t.y * uu.y + t.z * uu.z + t.w * uu.w;
    }
    #pragma unroll
    for (int j = 0; j < 4; ++j) {
        float4 t = g[10 + j], uu = *(const float4*)(u + 640 + 4 * (sub + 16 * j));
        l2 += t.x * uu.x + t.y * uu.y + t.z * uu.z + t.w * uu.w;
    }
    // butterfly over the token's 16 lanes -> every lane has the full sums
    #pragma unroll
    for (int m = 1; m < 16; m <<= 1) {
        l0 += __shfl_xor(l0, m);
        l1 += __shfl_xor(l1, m);
        l2 += __shfl_xor(l2, m);
    }
    l0 += lb[0]; l1 += lb[1]; l2 += lb[2];
    float mx = fmaxf(l0, fmaxf(l1, l2));
    float e0 = __expf(l0 - mx), e1 = __expf(l1 - mx), e2 = __expf(l2 - mx);
    float inv = 1.f / (e0 + e1 + e2);
    float a0 = e0 * inv, a1 = e1 * inv, a2 = e2 * inv;
    if (sub == 0) { alphaS[trow][0] = a0; alphaS[trow][1] = a1; alphaS[trow][2] = a2; }

    // ---- pack alpha-scaled bf16 into LDS (all writes within row pitch 218) ----
    #pragma unroll
    for (int j = 0; j < 5; ++j) {
        float4 t = g[j];
        Xd2[sub + 16 * j] = make_uint2(pack2bf(a0 * t.x, a0 * t.y), pack2bf(a0 * t.z, a0 * t.w));
    }
    #pragma unroll
    for (int j = 0; j < 5; ++j) {
        float4 t = g[5 + j];
        Xd2[80 + sub + 16 * j] = make_uint2(pack2bf(a1 * t.x, a1 * t.y), pack2bf(a1 * t.z, a1 * t.w));
    }
    #pragma unroll
    for (int j = 0; j < 3; ++j) {
        float4 t = g[10 + j];
        Xd2[160 + sub + 16 * j] = make_uint2(pack2bf(a2 * t.x, a2 * t.y), pack2bf(a2 * t.z, a2 * t.w));
    }
    if (sub < 2) {   // seg2 tail: only granules 48,49 are real data
        float4 t = g[13];
        Xd2[160 + 48 + sub] = make_uint2(pack2bf(a2 * t.x, a2 * t.y), pack2bf(a2 * t.z, a2 * t.w));
    }
    uint2 z2 = make_uint2(0u, 0u);
    for (int i = 75 + sub;  i < 80;  i += 16) Xd2[i] = z2;   // seg0 pad
    for (int i = 155 + sub; i < 160; i += 16) Xd2[i] = z2;   // seg1 pad
    for (int i = 210 + sub; i < 218; i += 16) Xd2[i] = z2;   // seg2 pad + row pad
    __syncthreads();

    // ---- MFMA GEMM: wave w owns N-tiles {2w, 2w+1}; single acc set ----
    int lane = tid & 63;
    int w = tid >> 6;               // 0..7
    int mrow = lane & 15;
    int kg8 = (lane >> 4) * 8;

    const ushort_t* bq0 = Wtf + ((size_t)((2 * w + 0) * 27) * 64 + lane) * 8;
    const ushort_t* bq1 = Wtf + ((size_t)((2 * w + 1) * 27) * 64 + lane) * 8;

    floatx4 acc[2][2];
    {
        floatx4 z = {0.f, 0.f, 0.f, 0.f};
        acc[0][0] = z; acc[0][1] = z; acc[1][0] = z; acc[1][1] = z;
    }

    #pragma unroll
    for (int kc = 0; kc < 27; ++kc) {
        short8 av0 = *(const short8*)&Xs[mrow][kc * 32 + kg8];
        short8 av1 = *(const short8*)&Xs[16 + mrow][kc * 32 + kg8];
        short8 bv0 = *(const short8*)(bq0 + kc * 512);
        short8 bv1 = *(const short8*)(bq1 + kc * 512);
        acc[0][0] = __builtin_amdgcn_mfma_f32_16x16x32_bf16(av0, bv0, acc[0][0], 0, 0, 0);
        acc[1][0] = __builtin_amdgcn_mfma_f32_16x16x32_bf16(av1, bv0, acc[1][0], 0, 0, 0);
        acc[0][1] = __builtin_amdgcn_mfma_f32_16x16x32_bf16(av0, bv1, acc[0][1], 0, 0, 0);
        acc[1][1] = __builtin_amdgcn_mfma_f32_16x16x32_bf16(av1, bv1, acc[1][1], 0, 0, 0);
    }

    // ---- epilogue: out = acc + a0*b0 + a1*b1 + a2*b2 (fp32) ----
    float bb0[2], bb1[2], bb2[2];
    #pragma unroll
    for (int nt = 0; nt < 2; ++nt) {
        int n = (2 * w + nt) * 16 + mrow;
        bb0[nt] = b0[n]; bb1[nt] = b1[n]; bb2[nt] = b2[n];
    }
    #pragma unroll
    for (int mt = 0; mt < 2; ++mt) {
        #pragma unroll
        for (int r = 0; r < 4; ++r) {
            int tok = mt * 16 + (lane >> 4) * 4 + r;
            float t0 = alphaS[tok][0], t1 = alphaS[tok][1], t2 = alphaS[tok][2];
            size_t rowoff = (size_t)(tok0 + tok) * DOUT;
            #pragma unroll
            for (int nt = 0; nt < 2; ++nt) {
                int n = (2 * w + nt) * 16 + mrow;
                out[rowoff + n] = acc[mt][nt][r] + t0 * bb0[nt] + t1 * bb1[nt] + t2 * bb2[nt];
            }
        }
    }
}

extern "C" void kernel_launch(void* const* d_in, const int* in_sizes, int n_in,
                              void* d_out, int out_size, void* d_ws, size_t ws_size,
                              hipStream_t stream) {
    const int*   ids = (const int*)d_in[0];
    const float* E0  = (const float*)d_in[1];
    const float* E1  = (const float*)d_in[2];
    const float* E2  = (const float*)d_in[3];
    const float* W0  = (const float*)d_in[4];
    const float* b0  = (const float*)d_in[5];
    const float* W1  = (const float*)d_in[6];
    const float* b1  = (const float*)d_in[7];
    const float* W2  = (const float*)d_in[8];
    const float* b2  = (const float*)d_in[9];
    const float* Wa  = (const float*)d_in[10];
    const float* ba  = (const float*)d_in[11];

    float* u      = (float*)d_ws;                       // 896 floats (zero-padded)
    float* lb     = u + 896;                            // 3 floats
    ushort_t* Wtf = (ushort_t*)((char*)d_ws + 4096);    // 432 KB fragment-ordered B

    k_prep<<<NPREP_T + NPREP_U, 256, 0, stream>>>(W0, W1, W2, b0, b1, b2, Wa, ba,
                                                  u, lb, Wtf);
    k_main<<<NTOK / TB, 512, 0, stream>>>(ids, E0, E1, E2, b0, b1, b2, u, lb, Wtf,
                                          (float*)d_out);
}